// Round 4
// baseline (261.977 us; speedup 1.0000x reference)
//
#include <hip/hip_runtime.h>
#include <cfloat>
#include <stdint.h>

// VQ argmin via exact-split f16 MFMA GEMM — R24: consolidation. R23 showed the
// 128x64 wave tile is latency-bound (16->8 waves/CU cost 29%); revert gemm to
// the verified R21 config (128x128 block, 2x2 waves of 64x64, direct-global,
// no K-loop barriers, 4 blocks/CU, reg-packed 64+64=128/wave). Keep R23's
// wins: atomicMin-fused reduction (rest 80->63us), split zsq, key-init in
// prep. New: extract folded into gemm via last-block-done counter (device
// atomics + threadfence; counter reset by prep each iteration -> graph-safe).
// 2 kernels/iteration instead of 3.
// Numerics bit-identical to all passers: same granule bytes, same 3-term MFMA
// order (av*bh, av*bl, aw*bh), same dist fp32(zsq - acc*2^-12), same u64 key
// min (atomicMin == sequential min; ties impossible since k differs).
#define KC 8192
#define NQ 8192
#define DD 256
#define NSTAGE 8

typedef _Float16 f16;
typedef _Float16 half8 __attribute__((ext_vector_type(8)));
typedef float floatx4 __attribute__((ext_vector_type(4)));

// ---- workspace maps ----
#define WS_AH   0
#define WS_AL   4194304
#define WS_BH   8388608
#define WS_BL1  12582912           // 1-pass: Bh/Bl 4MB each
#define WS_KEY1 16777216
#define WS_CNT1 16842752
#define WS_NEED1 (16842752ull + 128ull)   // 16.06 MB <= proven floor
#define WS_BL2  10485760           // 2-pass fallback: Bh/Bl 2MB each
#define WS_KEY2 12582912

// ---- device helpers ----
// B-prep (verified R4..R21 layout): gid = [ntl][s 8][q 4][n 128]; thread packs
// 8 d-values (d = s*32 + q*8 + j) of code (kofs + ntl*128 + n), hi/lo split.
__device__ __forceinline__ void prep_b_body(const float* __restrict__ cb,
                                            f16* __restrict__ Bh, f16* __restrict__ Bl,
                                            int kofs, int gid) {
    int n = gid & 127;
    int q = (gid >> 7) & 3;
    int s = (gid >> 9) & 7;
    int ntl = gid >> 12;
    int K = kofs + ntl * 128 + n;
    int d0 = s * 32 + q * 8;
    const float4 v0 = *(const float4*)(cb + (size_t)K * DD + d0);
    const float4 v1 = *(const float4*)(cb + (size_t)K * DD + d0 + 4);
    float vv[8] = {v0.x, v0.y, v0.z, v0.w, v1.x, v1.y, v1.z, v1.w};
    half8 eh8, el8;
    #pragma unroll
    for (int j = 0; j < 8; ++j) {
        float e = vv[j] * 8192.0f;               // exact pow2 scale
        f16 h = (f16)e;
        eh8[j] = h;
        el8[j] = (f16)(e - (float)h);
    }
    *(half8*)(Bh + (size_t)gid * 8) = eh8;
    *(half8*)(Bl + (size_t)gid * 8) = el8;
}

// A-prep (verified R4..R21 layout, byte-identical granules):
//   gid = ((mt*8+st)*4+q)*256 + r holds z[d=st*32+q*8+j][Q=mt*256+r] hi/lo.
__device__ __forceinline__ void prep_a_vec_body(const float* __restrict__ z,
                                                f16* __restrict__ Ah, f16* __restrict__ Al,
                                                int bid, int tid) {
    const int mt = bid >> 3;
    const int s  = bid & 7;
    const int q  = tid >> 6;
    const int lane = tid & 63;
    const int r0 = lane * 4;
    const int Q0 = mt * 256;
    const int b = Q0 >> 10;
    const int t0 = (Q0 & 1023) + r0;
    const float* zp = z + (size_t)b * (DD * 1024) + t0;
    const int d0 = s * 32 + q * 8;
    float4 v[8];
    #pragma unroll
    for (int j = 0; j < 8; ++j)
        v[j] = *(const float4*)(zp + (size_t)(d0 + j) * 1024);
    const size_t gbase = (((size_t)(mt * 8 + s) * 4 + q) * 256 + r0);
    #pragma unroll
    for (int dq = 0; dq < 4; ++dq) {
        half8 zh8, zl8;
        #pragma unroll
        for (int j = 0; j < 8; ++j) {
            float vv = (dq == 0) ? v[j].x : (dq == 1) ? v[j].y : (dq == 2) ? v[j].z : v[j].w;
            f16 h = (f16)vv;
            zh8[j] = h;
            zl8[j] = (f16)(vv - (float)h);       // exact fp32 residual
        }
        *(half8*)(Ah + (gbase + dq) * 8) = zh8;
        *(half8*)(Al + (gbase + dq) * 8) = zl8;
    }
}

// zsq split across 2 threads/query (exact partial chains of all passers;
// zsq[q] = s0 + s1 identical). Also inits key array and the done counter.
__device__ __forceinline__ void zsq2_body(const float* __restrict__ z,
                                          float* __restrict__ zsq,
                                          unsigned long long* __restrict__ key,
                                          unsigned int* __restrict__ done,
                                          int gid) {
    int q = gid >> 1, half = gid & 1;
    int b = q >> 10, t = q & 1023;
    const float* p = z + (size_t)b * (DD * 1024) + t + (size_t)(half * 128) * 1024;
    float s = 0.f;
    #pragma unroll 8
    for (int d = 0; d < 128; ++d) { float v = p[(size_t)d * 1024]; s = fmaf(v, v, s); }
    float so = __shfl_xor(s, 1, 64);             // partner half, same q
    if (half == 0) { zsq[q] = s + so; key[q] = ~0ull; }
    if (gid == 0 && done) *done = 0u;            // reset last-block counter
}

// ---- fused prep, long poles first:
//   blocks [0,64) zsq+key+cnt | [64,320) A-vec | [320,1344) B ----
__global__ void vq_prep_all(const float* __restrict__ z, const float* __restrict__ cb,
                            f16* __restrict__ Ah, f16* __restrict__ Al,
                            f16* __restrict__ Bh, f16* __restrict__ Bl,
                            float* __restrict__ zsq, unsigned long long* __restrict__ key,
                            unsigned int* __restrict__ done) {
    int bid = blockIdx.x;
    int tid = threadIdx.x;
    if (bid < 64) {
        zsq2_body(z, zsq, key, done, bid * 256 + tid);
    } else if (bid < 320) {
        prep_a_vec_body(z, Ah, Al, bid - 64, tid);
    } else {
        prep_b_body(cb, Bh, Bl, 0, (bid - 320) * 256 + tid);
    }
}

// standalone preps for the 2-pass fallback
__global__ void vq_prep_az(const float* __restrict__ z,
                           f16* __restrict__ Ah, f16* __restrict__ Al,
                           float* __restrict__ zsq, unsigned long long* __restrict__ key) {
    int bid = blockIdx.x;
    if (bid < 64) zsq2_body(z, zsq, key, nullptr, bid * 256 + threadIdx.x);
    else          prep_a_vec_body(z, Ah, Al, bid - 64, threadIdx.x);
}
__global__ void vq_prep_b(const float* __restrict__ cb,
                          f16* __restrict__ Bh, f16* __restrict__ Bl, int kofs) {
    prep_b_body(cb, Bh, Bl, kofs, blockIdx.x * 256 + threadIdx.x);
}

// ---- main GEMM (R21-verified body): 128x128 block, 2x2 waves of 64x64,
//      A and B direct from global (16B/lane coalesced, L2-resident), NO
//      barriers in the K-loop, reg-packed 64 VGPR + 64 AGPR = 128/wave.
//      Epilogue: atomicMin keys; last block writes out[] (extract folded). ----
__global__ __launch_bounds__(256, 4)
void vq_gemm16(const f16* __restrict__ Ah, const f16* __restrict__ Al,
               const f16* __restrict__ Bh, const f16* __restrict__ Bl,
               const float* __restrict__ zsq, unsigned long long* __restrict__ keyp,
               unsigned int* __restrict__ done, int* __restrict__ outp,
               int nblocks, int kofs) {
    // Swizzle (R12/R21-verified): per XCD, 8-ntl B chunks x 8 mh2 A tiles.
    const int flat = blockIdx.x;
    const int xcd = flat & 7;
    const int idx = flat >> 3;
    const int mh2 = xcd * 8 + ((idx >> 3) & 7);     // 0..63, 128-row tile
    const int ntl = (idx >> 6) * 8 + (idx & 7);     // 0..63 / 0..31
    const int tid = threadIdx.x;
    const int lane = tid & 63;
    const int wv = tid >> 6;
    const int wm = wv >> 1, wn = wv & 1;            // 2x2 waves of 64x64
    const int quad = lane >> 4;
    const int l16 = lane & 15;

    __shared__ unsigned long long kbuf[256];        // epilogue merge only
    __shared__ int slast;

    floatx4 acc[4][4];
    #pragma unroll
    for (int i = 0; i < 4; ++i)
        #pragma unroll
        for (int j = 0; j < 4; ++j) acc[i][j] = (floatx4)0.f;

    const int mt = mh2 >> 1;
    const int r0 = (mh2 & 1) * 128;
    // A fragment address in halfs (byte-identical granules to all passers):
    const size_t abase = ((((size_t)(mt * 8) * 4) + quad) * 256
                          + (size_t)(r0 + wm * 64 + l16)) * 8;
    const f16* Ap  = Ah + abase;
    const f16* Alp = Al + abase;
    const f16* Bpb = Bh + ((size_t)(ntl * 8) * 4 + quad) * 1024 + (size_t)(wn * 64 + l16) * 8;
    const f16* Blb = Bl + ((size_t)(ntl * 8) * 4 + quad) * 1024 + (size_t)(wn * 64 + l16) * 8;

    for (int s = 0; s < NSTAGE; ++s) {
        // ---- B fragments (8 x 1KB coalesced loads) ----
        half8 bhf[4], blf[4];
        #pragma unroll
        for (int nj = 0; nj < 4; ++nj) {
            bhf[nj] = *(const half8*)(Bpb + nj * 128);
            blf[nj] = *(const half8*)(Blb + nj * 128);
        }
        // ---- A fragments (16 x 1KB coalesced loads) ----
        half8 av[4], aw[4];
        #pragma unroll
        for (int mi = 0; mi < 4; ++mi) {
            av[mi] = *(const half8*)(Ap  + (size_t)mi * 128);
            aw[mi] = *(const half8*)(Alp + (size_t)mi * 128);
        }
        // ---- term-major MFMA (16 independent between dependent pairs) ----
        #pragma unroll
        for (int mi = 0; mi < 4; ++mi)
            #pragma unroll
            for (int nj = 0; nj < 4; ++nj)
                acc[mi][nj] = __builtin_amdgcn_mfma_f32_16x16x32_f16(av[mi], bhf[nj], acc[mi][nj], 0, 0, 0);
        #pragma unroll
        for (int mi = 0; mi < 4; ++mi)
            #pragma unroll
            for (int nj = 0; nj < 4; ++nj)
                acc[mi][nj] = __builtin_amdgcn_mfma_f32_16x16x32_f16(av[mi], blf[nj], acc[mi][nj], 0, 0, 0);
        #pragma unroll
        for (int mi = 0; mi < 4; ++mi)
            #pragma unroll
            for (int nj = 0; nj < 4; ++nj)
                acc[mi][nj] = __builtin_amdgcn_mfma_f32_16x16x32_f16(aw[mi], bhf[nj], acc[mi][nj], 0, 0, 0);
        // advance one K-stage: A granule group += 8192 halfs, B += 4096 halfs
        Ap  += 8192; Alp += 8192;
        Bpb += 4096; Blb += 4096;
    }

    // ---- epilogue (verified C/D map): dist quantization + 2-way merge +
    //      device-wide atomicMin (== sequential u64-min; ties impossible) ----
    const int kb = kofs + ntl * 128 + wn * 64;
    #pragma unroll
    for (int mi = 0; mi < 4; ++mi) {
        #pragma unroll
        for (int reg = 0; reg < 4; ++reg) {
            int qlocal = wm * 64 + mi * 16 + quad * 4 + reg;   // verified map
            float zq = zsq[mh2 * 128 + qlocal];
            float bd = FLT_MAX; int bk = 0;
            #pragma unroll
            for (int nj = 0; nj < 4; ++nj) {        // ascending k: '<' keeps lowest
                float dd = zq - acc[mi][nj][reg] * 0x1p-12f;  // single fp32 rounding
                int kk = kb + nj * 16 + l16;
                if (dd < bd || (dd == bd && kk < bk)) { bd = dd; bk = kk; }
            }
            #pragma unroll
            for (int mm = 1; mm <= 8; mm <<= 1) {   // 16-lane butterfly, same q
                float od = __shfl_xor(bd, mm, 64);
                int ok = __shfl_xor(bk, mm, 64);
                if (od < bd || (od == bd && ok < bk)) { bd = od; bk = ok; }
            }
            if (l16 == 0)
                kbuf[wn * 128 + qlocal] =
                    ((unsigned long long)__float_as_uint(bd) << 32) | (unsigned int)bk;
        }
    }
    __syncthreads();
    if (tid < 128) {
        unsigned long long k0 = kbuf[tid];
        unsigned long long k1 = kbuf[128 + tid];
        unsigned long long key = (k1 < k0) ? k1 : k0;
        atomicMin(&keyp[mh2 * 128 + tid], key);
    }
    if (!outp) return;
    // ---- last-block extract (folded kernel): all waves' atomics are drained
    //      before s_barrier; tid0 fences + bumps the device counter. ----
    __syncthreads();
    if (tid == 0) {
        __threadfence();
        slast = (atomicAdd(done, 1u) == (unsigned int)(nblocks - 1)) ? 1 : 0;
    }
    __syncthreads();
    if (slast) {
        for (int i = tid; i < NQ; i += 256) {
            unsigned long long v = atomicOr(&keyp[i], 0ull);   // device-scope read
            outp[i] = (int)(v & 0xFFFFFFFFull);
        }
    }
}

__global__ void vq_extract(const unsigned long long* __restrict__ key,
                           int* __restrict__ out) {
    int q = blockIdx.x * 256 + threadIdx.x;
    out[q] = (int)(key[q] & 0xFFFFFFFFull);
}

extern "C" void kernel_launch(void* const* d_in, const int* in_sizes, int n_in,
                              void* d_out, int out_size, void* d_ws, size_t ws_size,
                              hipStream_t stream) {
    const float* z  = (const float*)d_in[0];   // (8, 256, 1024) fp32
    const float* cb = (const float*)d_in[1];   // (8192, 256) fp32
    char* ws = (char*)d_ws;
    f16* Ah = (f16*)(ws + WS_AH);
    f16* Al = (f16*)(ws + WS_AL);
    // zsq parked in d_out (32 KB): read by gemm epilogues, then overwritten by
    // the last gemm block's extract (all zsq reads precede the counter hit).
    float* zsq = (float*)d_out;
    int* out = (int*)d_out;

    if (ws_size >= WS_NEED1) {
        f16* Bh = (f16*)(ws + WS_BH);
        f16* Bl = (f16*)(ws + WS_BL1);
        unsigned long long* key = (unsigned long long*)(ws + WS_KEY1);
        unsigned int* done = (unsigned int*)(ws + WS_CNT1);
        vq_prep_all<<<1344, 256, 0, stream>>>(z, cb, Ah, Al, Bh, Bl, zsq, key, done);
        vq_gemm16<<<4096, 256, 0, stream>>>(Ah, Al, Bh, Bl, zsq, key, done, out, 4096, 0);
        // no extract kernel: folded into the last gemm block
    } else {
        // 2-pass fallback (12.06 MB): B buffer reused across halves of K.
        f16* Bh = (f16*)(ws + WS_BH);
        f16* Bl = (f16*)(ws + WS_BL2);
        unsigned long long* key = (unsigned long long*)(ws + WS_KEY2);
        vq_prep_az<<<320, 256, 0, stream>>>(z, Ah, Al, zsq, key);
        for (int p = 0; p < 2; ++p) {
            int kofs = p * 4096;
            vq_prep_b<<<512, 256, 0, stream>>>(cb, Bh, Bl, kofs);
            vq_gemm16<<<2048, 256, 0, stream>>>(Ah, Al, Bh, Bl, zsq, key,
                                                nullptr, nullptr, 2048, kofs);
        }
        vq_extract<<<NQ / 256, 256, 0, stream>>>(key, out);
    }
}

// Round 5
// 187.884 us; speedup vs baseline: 1.3944x; 1.3944x over previous
//
#include <hip/hip_runtime.h>
#include <cfloat>
#include <stdint.h>

// VQ argmin via exact-split f16 MFMA GEMM — R25: clean base. R24's regression
// (gemm 119->195, MfmaUtil 37->22, FETCH unchanged) is attributed to the
// per-block __threadfence (agent-scope release = L2 writeback/invalidate on
// non-coherent-L2 gfx950; 4096 invalidations destroy A/B L2 residency for
// in-flight blocks). R25 removes fence + fold entirely; gemm is R21-verbatim
// (128x128 block, 2x2 waves of 64x64, direct-global, no K-loop barriers,
// reg-packed 64 VGPR + 64 AGPR = 4 blocks/CU) except the final merge is a
// fire-and-forget device-scope atomicMin into a 64KB key array (measures
// atomicMin cost cleanly: predict <=5us). Rest keeps R23's verified wins:
// prep ordering, split zsq, key-init in prep, tiny extract kernel.
// Numerics bit-identical to all passers: same granule bytes, same 3-term MFMA
// order (av*bh, av*bl, aw*bh), same dist fp32(zsq - acc*2^-12), same u64 key
// min (atomicMin == sequential min; ties impossible since k differs).
#define KC 8192
#define NQ 8192
#define DD 256
#define NSTAGE 8

typedef _Float16 f16;
typedef _Float16 half8 __attribute__((ext_vector_type(8)));
typedef float floatx4 __attribute__((ext_vector_type(4)));

// ---- workspace maps ----
#define WS_AH   0
#define WS_AL   4194304
#define WS_BH   8388608
#define WS_BL1  12582912           // 1-pass: Bh/Bl 4MB each
#define WS_KEY1 16777216
#define WS_NEED1 (16777216ull + 65536ull)   // 16.06 MiB (<= every observed ws)
#define WS_BL2  10485760           // 2-pass fallback: Bh/Bl 2MB each
#define WS_KEY2 12582912

// ---- device helpers ----
// B-prep (verified R4..R21 layout): gid = [ntl][s 8][q 4][n 128]; thread packs
// 8 d-values (d = s*32 + q*8 + j) of code (kofs + ntl*128 + n), hi/lo split.
__device__ __forceinline__ void prep_b_body(const float* __restrict__ cb,
                                            f16* __restrict__ Bh, f16* __restrict__ Bl,
                                            int kofs, int gid) {
    int n = gid & 127;
    int q = (gid >> 7) & 3;
    int s = (gid >> 9) & 7;
    int ntl = gid >> 12;
    int K = kofs + ntl * 128 + n;
    int d0 = s * 32 + q * 8;
    const float4 v0 = *(const float4*)(cb + (size_t)K * DD + d0);
    const float4 v1 = *(const float4*)(cb + (size_t)K * DD + d0 + 4);
    float vv[8] = {v0.x, v0.y, v0.z, v0.w, v1.x, v1.y, v1.z, v1.w};
    half8 eh8, el8;
    #pragma unroll
    for (int j = 0; j < 8; ++j) {
        float e = vv[j] * 8192.0f;               // exact pow2 scale
        f16 h = (f16)e;
        eh8[j] = h;
        el8[j] = (f16)(e - (float)h);
    }
    *(half8*)(Bh + (size_t)gid * 8) = eh8;
    *(half8*)(Bl + (size_t)gid * 8) = el8;
}

// A-prep (verified R4..R21 layout, byte-identical granules):
//   gid = ((mt*8+st)*4+q)*256 + r holds z[d=st*32+q*8+j][Q=mt*256+r] hi/lo.
__device__ __forceinline__ void prep_a_vec_body(const float* __restrict__ z,
                                                f16* __restrict__ Ah, f16* __restrict__ Al,
                                                int bid, int tid) {
    const int mt = bid >> 3;
    const int s  = bid & 7;
    const int q  = tid >> 6;
    const int lane = tid & 63;
    const int r0 = lane * 4;
    const int Q0 = mt * 256;
    const int b = Q0 >> 10;
    const int t0 = (Q0 & 1023) + r0;
    const float* zp = z + (size_t)b * (DD * 1024) + t0;
    const int d0 = s * 32 + q * 8;
    float4 v[8];
    #pragma unroll
    for (int j = 0; j < 8; ++j)
        v[j] = *(const float4*)(zp + (size_t)(d0 + j) * 1024);
    const size_t gbase = (((size_t)(mt * 8 + s) * 4 + q) * 256 + r0);
    #pragma unroll
    for (int dq = 0; dq < 4; ++dq) {
        half8 zh8, zl8;
        #pragma unroll
        for (int j = 0; j < 8; ++j) {
            float vv = (dq == 0) ? v[j].x : (dq == 1) ? v[j].y : (dq == 2) ? v[j].z : v[j].w;
            f16 h = (f16)vv;
            zh8[j] = h;
            zl8[j] = (f16)(vv - (float)h);       // exact fp32 residual
        }
        *(half8*)(Ah + (gbase + dq) * 8) = zh8;
        *(half8*)(Al + (gbase + dq) * 8) = zl8;
    }
}

// zsq split across 2 threads/query (exact partial chains of all passers;
// zsq[q] = s0 + s1 identical). Also inits the atomic key array.
__device__ __forceinline__ void zsq2_body(const float* __restrict__ z,
                                          float* __restrict__ zsq,
                                          unsigned long long* __restrict__ key,
                                          int gid) {
    int q = gid >> 1, half = gid & 1;
    int b = q >> 10, t = q & 1023;
    const float* p = z + (size_t)b * (DD * 1024) + t + (size_t)(half * 128) * 1024;
    float s = 0.f;
    #pragma unroll 8
    for (int d = 0; d < 128; ++d) { float v = p[(size_t)d * 1024]; s = fmaf(v, v, s); }
    float so = __shfl_xor(s, 1, 64);             // partner half, same q
    if (half == 0) { zsq[q] = s + so; key[q] = ~0ull; }
}

// ---- fused prep, long poles first:
//   blocks [0,64) zsq+key-init | [64,320) A-vec | [320,1344) B ----
__global__ void vq_prep_all(const float* __restrict__ z, const float* __restrict__ cb,
                            f16* __restrict__ Ah, f16* __restrict__ Al,
                            f16* __restrict__ Bh, f16* __restrict__ Bl,
                            float* __restrict__ zsq, unsigned long long* __restrict__ key) {
    int bid = blockIdx.x;
    int tid = threadIdx.x;
    if (bid < 64) {
        zsq2_body(z, zsq, key, bid * 256 + tid);
    } else if (bid < 320) {
        prep_a_vec_body(z, Ah, Al, bid - 64, tid);
    } else {
        prep_b_body(cb, Bh, Bl, 0, (bid - 320) * 256 + tid);
    }
}

// standalone preps for the 2-pass fallback
__global__ void vq_prep_az(const float* __restrict__ z,
                           f16* __restrict__ Ah, f16* __restrict__ Al,
                           float* __restrict__ zsq, unsigned long long* __restrict__ key) {
    int bid = blockIdx.x;
    if (bid < 64) zsq2_body(z, zsq, key, bid * 256 + threadIdx.x);
    else          prep_a_vec_body(z, Ah, Al, bid - 64, threadIdx.x);
}
__global__ void vq_prep_b(const float* __restrict__ cb,
                          f16* __restrict__ Bh, f16* __restrict__ Bl, int kofs) {
    prep_b_body(cb, Bh, Bl, kofs, blockIdx.x * 256 + threadIdx.x);
}

// ---- main GEMM (R21-verified body): 128x128 block, 2x2 waves of 64x64,
//      A and B direct from global (16B/lane coalesced, L2-resident), NO
//      barriers in the K-loop, reg-packed 64 VGPR + 64 AGPR = 128/wave.
//      Epilogue: fire-and-forget device-scope atomicMin (no fence/fold). ----
__global__ __launch_bounds__(256, 4)
void vq_gemm16(const f16* __restrict__ Ah, const f16* __restrict__ Al,
               const f16* __restrict__ Bh, const f16* __restrict__ Bl,
               const float* __restrict__ zsq, unsigned long long* __restrict__ keyp,
               int kofs) {
    // Swizzle (R12/R21-verified): per XCD, 8-ntl B chunks x 8 mh2 A tiles.
    const int flat = blockIdx.x;
    const int xcd = flat & 7;
    const int idx = flat >> 3;
    const int mh2 = xcd * 8 + ((idx >> 3) & 7);     // 0..63, 128-row tile
    const int ntl = (idx >> 6) * 8 + (idx & 7);     // 0..63 / 0..31
    const int tid = threadIdx.x;
    const int lane = tid & 63;
    const int wv = tid >> 6;
    const int wm = wv >> 1, wn = wv & 1;            // 2x2 waves of 64x64
    const int quad = lane >> 4;
    const int l16 = lane & 15;

    __shared__ unsigned long long kbuf[256];        // epilogue merge only

    floatx4 acc[4][4];
    #pragma unroll
    for (int i = 0; i < 4; ++i)
        #pragma unroll
        for (int j = 0; j < 4; ++j) acc[i][j] = (floatx4)0.f;

    const int mt = mh2 >> 1;
    const int r0 = (mh2 & 1) * 128;
    // A fragment address in halfs (byte-identical granules to all passers):
    const size_t abase = ((((size_t)(mt * 8) * 4) + quad) * 256
                          + (size_t)(r0 + wm * 64 + l16)) * 8;
    const f16* Ap  = Ah + abase;
    const f16* Alp = Al + abase;
    const f16* Bpb = Bh + ((size_t)(ntl * 8) * 4 + quad) * 1024 + (size_t)(wn * 64 + l16) * 8;
    const f16* Blb = Bl + ((size_t)(ntl * 8) * 4 + quad) * 1024 + (size_t)(wn * 64 + l16) * 8;

    for (int s = 0; s < NSTAGE; ++s) {
        // ---- B fragments (8 x 1KB coalesced loads) ----
        half8 bhf[4], blf[4];
        #pragma unroll
        for (int nj = 0; nj < 4; ++nj) {
            bhf[nj] = *(const half8*)(Bpb + nj * 128);
            blf[nj] = *(const half8*)(Blb + nj * 128);
        }
        // ---- A fragments (8 x 1KB coalesced loads) ----
        half8 av[4], aw[4];
        #pragma unroll
        for (int mi = 0; mi < 4; ++mi) {
            av[mi] = *(const half8*)(Ap  + (size_t)mi * 128);
            aw[mi] = *(const half8*)(Alp + (size_t)mi * 128);
        }
        // ---- term-major MFMA (16 independent between dependent pairs) ----
        #pragma unroll
        for (int mi = 0; mi < 4; ++mi)
            #pragma unroll
            for (int nj = 0; nj < 4; ++nj)
                acc[mi][nj] = __builtin_amdgcn_mfma_f32_16x16x32_f16(av[mi], bhf[nj], acc[mi][nj], 0, 0, 0);
        #pragma unroll
        for (int mi = 0; mi < 4; ++mi)
            #pragma unroll
            for (int nj = 0; nj < 4; ++nj)
                acc[mi][nj] = __builtin_amdgcn_mfma_f32_16x16x32_f16(av[mi], blf[nj], acc[mi][nj], 0, 0, 0);
        #pragma unroll
        for (int mi = 0; mi < 4; ++mi)
            #pragma unroll
            for (int nj = 0; nj < 4; ++nj)
                acc[mi][nj] = __builtin_amdgcn_mfma_f32_16x16x32_f16(aw[mi], bhf[nj], acc[mi][nj], 0, 0, 0);
        // advance one K-stage: A granule group += 8192 halfs, B += 4096 halfs
        Ap  += 8192; Alp += 8192;
        Bpb += 4096; Blb += 4096;
    }

    // ---- epilogue (verified C/D map): dist quantization + 2-way merge +
    //      device-wide atomicMin (== sequential u64-min; ties impossible) ----
    const int kb = kofs + ntl * 128 + wn * 64;
    #pragma unroll
    for (int mi = 0; mi < 4; ++mi) {
        #pragma unroll
        for (int reg = 0; reg < 4; ++reg) {
            int qlocal = wm * 64 + mi * 16 + quad * 4 + reg;   // verified map
            float zq = zsq[mh2 * 128 + qlocal];
            float bd = FLT_MAX; int bk = 0;
            #pragma unroll
            for (int nj = 0; nj < 4; ++nj) {        // ascending k: '<' keeps lowest
                float dd = zq - acc[mi][nj][reg] * 0x1p-12f;  // single fp32 rounding
                int kk = kb + nj * 16 + l16;
                if (dd < bd || (dd == bd && kk < bk)) { bd = dd; bk = kk; }
            }
            #pragma unroll
            for (int mm = 1; mm <= 8; mm <<= 1) {   // 16-lane butterfly, same q
                float od = __shfl_xor(bd, mm, 64);
                int ok = __shfl_xor(bk, mm, 64);
                if (od < bd || (od == bd && ok < bk)) { bd = od; bk = ok; }
            }
            if (l16 == 0)
                kbuf[wn * 128 + qlocal] =
                    ((unsigned long long)__float_as_uint(bd) << 32) | (unsigned int)bk;
        }
    }
    __syncthreads();
    if (tid < 128) {
        unsigned long long k0 = kbuf[tid];
        unsigned long long k1 = kbuf[128 + tid];
        unsigned long long key = (k1 < k0) ? k1 : k0;
        atomicMin(&keyp[mh2 * 128 + tid], key);     // fire-and-forget, no fence
    }
}

__global__ void vq_extract(const unsigned long long* __restrict__ key,
                           int* __restrict__ out) {
    int q = blockIdx.x * 256 + threadIdx.x;
    out[q] = (int)(key[q] & 0xFFFFFFFFull);
}

extern "C" void kernel_launch(void* const* d_in, const int* in_sizes, int n_in,
                              void* d_out, int out_size, void* d_ws, size_t ws_size,
                              hipStream_t stream) {
    const float* z  = (const float*)d_in[0];   // (8, 256, 1024) fp32
    const float* cb = (const float*)d_in[1];   // (8192, 256) fp32
    char* ws = (char*)d_ws;
    f16* Ah = (f16*)(ws + WS_AH);
    f16* Al = (f16*)(ws + WS_AL);
    // zsq parked in d_out (32 KB): read by gemm, overwritten by extract.
    float* zsq = (float*)d_out;
    int* out = (int*)d_out;

    if (ws_size >= WS_NEED1) {
        f16* Bh = (f16*)(ws + WS_BH);
        f16* Bl = (f16*)(ws + WS_BL1);
        unsigned long long* key = (unsigned long long*)(ws + WS_KEY1);
        vq_prep_all<<<1344, 256, 0, stream>>>(z, cb, Ah, Al, Bh, Bl, zsq, key);
        vq_gemm16<<<4096, 256, 0, stream>>>(Ah, Al, Bh, Bl, zsq, key, 0);
        vq_extract<<<NQ / 256, 256, 0, stream>>>(key, out);
    } else {
        // 2-pass fallback (12.06 MB): B buffer reused across halves of K.
        f16* Bh = (f16*)(ws + WS_BH);
        f16* Bl = (f16*)(ws + WS_BL2);
        unsigned long long* key = (unsigned long long*)(ws + WS_KEY2);
        vq_prep_az<<<320, 256, 0, stream>>>(z, Ah, Al, zsq, key);
        for (int p = 0; p < 2; ++p) {
            int kofs = p * 4096;
            vq_prep_b<<<512, 256, 0, stream>>>(cb, Bh, Bl, kofs);
            vq_gemm16<<<2048, 256, 0, stream>>>(Ah, Al, Bh, Bl, zsq, key, kofs);
        }
        vq_extract<<<NQ / 256, 256, 0, stream>>>(key, out);
    }
}